// Round 5
// baseline (368.779 us; speedup 1.0000x reference)
//
#include <hip/hip_runtime.h>
#include <hip/hip_bf16.h>
#include <cstddef>

// ---- problem constants ----
#define Bc   2
#define Lc   8192
#define TGT  6146          // L - RF, RF = 2046
#define NL   20            // layers
#define RCc  32
#define DCc  32
#define SCc  1024
#define ECc  512
#define OCc  256
#define KTOT (NL * DCc)    // 640
#define TTILES 49          // ceil(TGT/128)

typedef __attribute__((ext_vector_type(4))) float f32x4;
typedef __attribute__((ext_vector_type(8))) short bf16x8;
typedef __attribute__((ext_vector_type(4))) int i32x4;
typedef __attribute__((ext_vector_type(2))) int i32x2;

typedef __attribute__((address_space(1))) void* as1v;
typedef __attribute__((address_space(3))) void* as3v;

// ============================================================
// K0: input 1x1 conv  (B,256,L) x (32,256) -> res (B,32,L)
// ============================================================
__global__ __launch_bounds__(256) void input_conv(
    const float* __restrict__ x,   // [B][256][L]
    const float* __restrict__ w,   // [32][256]
    float* __restrict__ res_out)   // [B][32][L]
{
    __shared__ float ws[32][256];
    __shared__ float xs[64][64];
    int tid = threadIdx.x;
    int b   = blockIdx.y;
    int t0  = blockIdx.x * 64;

    for (int idx = tid; idx < 32 * 256; idx += 256)
        ws[idx >> 8][idx & 255] = w[idx];

    int tl = tid & 63, qq = tid >> 6, oc0 = qq * 8;
    float acc[8] = {};

    for (int icc = 0; icc < 4; ++icc) {
        __syncthreads();
        for (int idx = tid; idx < 64 * 64; idx += 256) {
            int icl = idx >> 6, tll = idx & 63;
            xs[icl][tll] = x[((size_t)b * 256 + icc * 64 + icl) * Lc + t0 + tll];
        }
        __syncthreads();
        for (int icl = 0; icl < 64; icl += 4) {
            float x0 = xs[icl][tl], x1 = xs[icl + 1][tl];
            float x2 = xs[icl + 2][tl], x3 = xs[icl + 3][tl];
#pragma unroll
            for (int j = 0; j < 8; ++j) {
                const float4 w4 = *(const float4*)&ws[oc0 + j][icc * 64 + icl];
                acc[j] += w4.x * x0 + w4.y * x1 + w4.z * x2 + w4.w * x3;
            }
        }
    }
#pragma unroll
    for (int j = 0; j < 8; ++j)
        res_out[((size_t)b * 32 + oc0 + j) * Lc + t0 + tl] = acc[j];
}

// ============================================================
// per-layer v3: 256 thr, 64-t tile, thread = (p in [0,32), quad).
// 2 positions per thread (p, p+32) -> each weight b128 broadcast
// feeds 8 FMA. x columns in registers; residual init from regs.
// ============================================================
template <bool SKIPRES>
__global__ __launch_bounds__(256) void layer_v3(
    const float* __restrict__ res_in,   // [B][32][L]
    float* __restrict__ res_out,        // [B][32][L]
    __hip_bfloat16* __restrict__ outsT, // [B*TGT][640]
    const float* __restrict__ filt,     // [32][32][2]
    const float* __restrict__ gate,     // [32][32][2]
    const float* __restrict__ resw,     // [32][32]
    const float* __restrict__ cond,     // [B][5]
    const float* __restrict__ gcf,      // [5]
    const float* __restrict__ gcs,      // [5]
    int dil, int li)
{
    __shared__ __align__(16) float sFT[2][32][32];  // [tap][ic][oc]
    __shared__ __align__(16) float sGT[2][32][32];
    __shared__ __align__(16) float sRT[32][32];     // [ic][oc]
    __shared__ float osh[32][64];

    int tid = threadIdx.x;
    int b   = blockIdx.y;
    int t0  = blockIdx.x * 64;
    int p   = tid & 31, q = tid >> 5;   // q in 0..7
    int oc0 = q * 4;
    int tA  = t0 + p, tB = t0 + p + 32;

    // stage weights (coalesced global reads, transposed LDS writes)
    for (int idx = tid; idx < 2048; idx += 256) {
        int oc = idx >> 6, ic = (idx >> 1) & 31, s = idx & 1;
        sFT[s][ic][oc] = filt[idx];
        sGT[s][ic][oc] = gate[idx];
    }
    for (int idx = tid; idx < 1024; idx += 256)
        sRT[idx & 31][idx >> 5] = resw[idx];

    // x columns into registers
    const float* rbase = res_in + (size_t)b * 32 * Lc;
    float x0a[32], x0b[32], xma[32], xmb[32];
#pragma unroll
    for (int ic = 0; ic < 32; ++ic) {
        x0a[ic] = rbase[ic * Lc + tA];
        x0b[ic] = rbase[ic * Lc + tB];
        xma[ic] = (tA >= dil) ? rbase[ic * Lc + tA - dil] : 0.f;
        xmb[ic] = (tB >= dil) ? rbase[ic * Lc + tB - dil] : 0.f;
    }

    float gf = gcf[0] * cond[b * 5 + 0] + gcf[1] * cond[b * 5 + 1] +
               gcf[2] * cond[b * 5 + 2] + gcf[3] * cond[b * 5 + 3] +
               gcf[4] * cond[b * 5 + 4];
    float gg = gcs[0] * cond[b * 5 + 0] + gcs[1] * cond[b * 5 + 1] +
               gcs[2] * cond[b * 5 + 2] + gcs[3] * cond[b * 5 + 3] +
               gcs[4] * cond[b * 5 + 4];

    __syncthreads();   // weights staged

    float fa[4], ga[4], fb[4], gb[4];
#pragma unroll
    for (int j = 0; j < 4; ++j) { fa[j] = gf; ga[j] = gg; fb[j] = gf; gb[j] = gg; }

#pragma unroll
    for (int ic = 0; ic < 32; ++ic) {
        const float4 f0 = *(const float4*)&sFT[0][ic][oc0];
        const float4 f1 = *(const float4*)&sFT[1][ic][oc0];
        const float4 g0 = *(const float4*)&sGT[0][ic][oc0];
        const float4 g1 = *(const float4*)&sGT[1][ic][oc0];
        float a1 = xma[ic], c1 = x0a[ic];
        float a2 = xmb[ic], c2 = x0b[ic];
        fa[0] += f0.x * a1 + f1.x * c1;  ga[0] += g0.x * a1 + g1.x * c1;
        fa[1] += f0.y * a1 + f1.y * c1;  ga[1] += g0.y * a1 + g1.y * c1;
        fa[2] += f0.z * a1 + f1.z * c1;  ga[2] += g0.z * a1 + g1.z * c1;
        fa[3] += f0.w * a1 + f1.w * c1;  ga[3] += g0.w * a1 + g1.w * c1;
        fb[0] += f0.x * a2 + f1.x * c2;  gb[0] += g0.x * a2 + g1.x * c2;
        fb[1] += f0.y * a2 + f1.y * c2;  gb[1] += g0.y * a2 + g1.y * c2;
        fb[2] += f0.z * a2 + f1.z * c2;  gb[2] += g0.z * a2 + g1.z * c2;
        fb[3] += f0.w * a2 + f1.w * c2;  gb[3] += g0.w * a2 + g1.w * c2;
    }

    float oa[4], ob[4];
#pragma unroll
    for (int j = 0; j < 4; ++j) {
        float tha = 1.f - 2.f / (__expf(2.f * fa[j]) + 1.f);
        float sga = 1.f / (1.f + __expf(-ga[j]));
        oa[j] = tha * sga;
        osh[oc0 + j][p] = oa[j];
        float thb = 1.f - 2.f / (__expf(2.f * fb[j]) + 1.f);
        float sgb = 1.f / (1.f + __expf(-gb[j]));
        ob[j] = thb * sgb;
        osh[oc0 + j][p + 32] = ob[j];
    }

    // skip-output stores (bf16, time-major), 8B per store
    if (tA >= Lc - TGT) {
        int ts = tA - (Lc - TGT);
        union { i32x2 v; __hip_bfloat16 h[4]; } u;
#pragma unroll
        for (int j = 0; j < 4; ++j) u.h[j] = __float2bfloat16(oa[j]);
        *(i32x2*)(outsT + ((size_t)(b * TGT + ts)) * KTOT + li * 32 + oc0) = u.v;
    }
    if (tB >= Lc - TGT) {
        int ts = tB - (Lc - TGT);
        union { i32x2 v; __hip_bfloat16 h[4]; } u;
#pragma unroll
        for (int j = 0; j < 4; ++j) u.h[j] = __float2bfloat16(ob[j]);
        *(i32x2*)(outsT + ((size_t)(b * TGT + ts)) * KTOT + li * 32 + oc0) = u.v;
    }

    if (!SKIPRES) {
        __syncthreads();   // osh complete
        float ra[4], rb[4];
#pragma unroll
        for (int j = 0; j < 4; ++j) { ra[j] = x0a[oc0 + j]; rb[j] = x0b[oc0 + j]; }
#pragma unroll
        for (int ic = 0; ic < 32; ++ic) {
            float ova = osh[ic][p];
            float ovb = osh[ic][p + 32];
            const float4 w4 = *(const float4*)&sRT[ic][oc0];
            ra[0] += w4.x * ova;  rb[0] += w4.x * ovb;
            ra[1] += w4.y * ova;  rb[1] += w4.y * ovb;
            ra[2] += w4.z * ova;  rb[2] += w4.z * ovb;
            ra[3] += w4.w * ova;  rb[3] += w4.w * ovb;
        }
#pragma unroll
        for (int j = 0; j < 4; ++j) {
            res_out[((size_t)b * 32 + oc0 + j) * Lc + tA] = ra[j];
            res_out[((size_t)b * 32 + oc0 + j) * Lc + tB] = rb[j];
        }
    }
}

// ============================================================
// weight packs (fp32 -> bf16, [M][K] row-major)
// ============================================================
__global__ void pack_w1(const float* __restrict__ sw, __hip_bfloat16* __restrict__ d)
{
    int idx = blockIdx.x * 256 + threadIdx.x;
    if (idx >= SCc * KTOT) return;
    int m = idx / KTOT, k = idx % KTOT;
    int i = k >> 5, c = k & 31;
    d[idx] = __float2bfloat16(sw[((size_t)i * SCc + m) * DCc + c]);
}

__global__ void pack_plain(const float* __restrict__ s, __hip_bfloat16* __restrict__ d, int n)
{
    int idx = blockIdx.x * 256 + threadIdx.x;
    if (idx < n) d[idx] = __float2bfloat16(s[idx]);
}

// ============================================================
// bf16 MFMA GEMM: Y[t][m] = sum_k X[t][k] * W[m][k]  (+bias, relu)
// Staging via global_load_lds width=16: LDS dest linear
// (HW: wave-uniform base + lane*16), swizzle achieved by
// inverse-swizzling the per-lane GLOBAL source address.
// slot s holds (row r = s>>3, granule g = (s&7)^(r&7));
// per lane: subrow = lane>>3, g = (lane&7)^subrow (const per lane).
// ============================================================
template <bool RELU_OUT, bool OUT_BF16>
__global__ __launch_bounds__(256) void gemm_mfma(
    const __hip_bfloat16* __restrict__ X,
    const __hip_bfloat16* __restrict__ W,
    const float* __restrict__ bias,
    void* __restrict__ Y,
    int M, int K)
{
    __shared__ i32x4 Xs[128 * 8];
    __shared__ i32x4 Ws[128 * 8];

    int tid = threadIdx.x;
    int m0  = blockIdx.x * 128;
    int by  = blockIdx.y;
    int b   = by / TTILES;
    int t0  = (by % TTILES) * 128;

    int lane = tid & 63, wid = tid >> 6;
    int wy = wid >> 1, wx = wid & 1;
    int r15 = lane & 15, q = lane >> 4;

    // gld_lds staging geometry
    int subrow = lane >> 3;        // 0..7
    int g      = (lane & 7) ^ subrow;   // granule, fixed per lane
    const __hip_bfloat16* xp[4];
    const __hip_bfloat16* wp[4];
#pragma unroll
    for (int i = 0; i < 4; ++i) {
        int r = wid * 32 + i * 8 + subrow;
        int xrow = t0 + r; if (xrow > TGT - 1) xrow = TGT - 1;
        xp[i] = X + ((size_t)(b * TGT + xrow)) * K + g * 8;
        wp[i] = W + ((size_t)(m0 + r)) * K + g * 8;
    }

    f32x4 acc[4][4] = {};

    const int nkt = K >> 6;
    for (int kt = 0; kt < nkt; ++kt) {
        __syncthreads();   // prev tile fully consumed
#pragma unroll
        for (int i = 0; i < 4; ++i) {
            __builtin_amdgcn_global_load_lds((as1v)(void*)xp[i],
                (as3v)(void*)&Xs[(wid * 4 + i) * 64], 16, 0, 0);
            __builtin_amdgcn_global_load_lds((as1v)(void*)wp[i],
                (as3v)(void*)&Ws[(wid * 4 + i) * 64], 16, 0, 0);
            xp[i] += 64;
            wp[i] += 64;
        }
        __syncthreads();   // vmcnt(0) drained by barrier -> tile ready

        const bf16x8* Xv = (const bf16x8*)Xs;
        const bf16x8* Wv = (const bf16x8*)Ws;
#pragma unroll
        for (int kk = 0; kk < 2; ++kk) {
            int sg = (kk * 4 + q) ^ (r15 & 7);
            bf16x8 af[4], bw[4];
#pragma unroll
            for (int ft = 0; ft < 4; ++ft)
                af[ft] = Xv[(wy * 64 + ft * 16 + r15) * 8 + sg];
#pragma unroll
            for (int fj = 0; fj < 4; ++fj)
                bw[fj] = Wv[(wx * 64 + fj * 16 + r15) * 8 + sg];
#pragma unroll
            for (int ft = 0; ft < 4; ++ft)
#pragma unroll
                for (int fj = 0; fj < 4; ++fj)
                    acc[ft][fj] = __builtin_amdgcn_mfma_f32_16x16x32_bf16(
                        af[ft], bw[fj], acc[ft][fj], 0, 0, 0);
        }
    }

#pragma unroll
    for (int ft = 0; ft < 4; ++ft) {
#pragma unroll
        for (int r = 0; r < 4; ++r) {
            int t = t0 + wy * 64 + ft * 16 + q * 4 + r;
            if (t < TGT) {
                size_t rowoff = ((size_t)(b * TGT + t)) * M;
#pragma unroll
                for (int fj = 0; fj < 4; ++fj) {
                    int m = m0 + wx * 64 + fj * 16 + r15;
                    float v = acc[ft][fj][r];
                    if (bias) v += bias[m];
                    if (RELU_OUT) v = fmaxf(v, 0.f);
                    if (OUT_BF16)
                        ((__hip_bfloat16*)Y)[rowoff + m] = __float2bfloat16(v);
                    else
                        ((float*)Y)[rowoff + m] = v;
                }
            }
        }
    }
}

// ============================================================
extern "C" void kernel_launch(void* const* d_in, const int* in_sizes, int n_in,
                              void* d_out, int out_size, void* d_ws, size_t ws_size,
                              hipStream_t stream)
{
    const float* inputs   = (const float*)d_in[0];
    const float* cond     = (const float*)d_in[1];
    const float* input_w  = (const float*)d_in[2];
    const float* filter_w = (const float*)d_in[3];
    const float* gate_w   = (const float*)d_in[4];
    const float* res_w    = (const float*)d_in[5];
    const float* split_w  = (const float*)d_in[6];
    const float* gcf_w    = (const float*)d_in[7];
    const float* gcs_w    = (const float*)d_in[8];
    const float* f1_w     = (const float*)d_in[9];
    const float* f1_b     = (const float*)d_in[10];
    const float* f2_w     = (const float*)d_in[11];
    const float* f2_b     = (const float*)d_in[12];
    float* out = (float*)d_out;

    char* wsb = (char*)d_ws;
    const size_t RES_B   = (size_t)Bc * RCc * Lc * 4;        // 2 MB each
    const size_t OUTS_B  = (size_t)Bc * TGT * KTOT * 2;      // 15.7 MB
    const size_t FIN_B   = (size_t)Bc * TGT * SCc * 2;       // 25.2 MB
    const size_t H1_B    = (size_t)Bc * TGT * ECc * 2;       // 12.6 MB
    const size_t W1_B    = (size_t)SCc * KTOT * 2;
    const size_t W2_B    = (size_t)ECc * SCc * 2;

    float* res0              = (float*)wsb;                   size_t off = RES_B;
    float* res1              = (float*)(wsb + off);           off += RES_B;
    __hip_bfloat16* outsT    = (__hip_bfloat16*)(wsb + off);  off += OUTS_B;
    __hip_bfloat16* finalT   = (__hip_bfloat16*)(wsb + off);  off += FIN_B;
    __hip_bfloat16* h1T      = (__hip_bfloat16*)(wsb + off);  off += H1_B;
    __hip_bfloat16* Wp1      = (__hip_bfloat16*)(wsb + off);  off += W1_B;
    __hip_bfloat16* Wp2      = (__hip_bfloat16*)(wsb + off);  off += W2_B;
    __hip_bfloat16* Wp3      = (__hip_bfloat16*)(wsb + off);

    // weight packs (independent of activations)
    pack_w1<<<(SCc * KTOT + 255) / 256, 256, 0, stream>>>(split_w, Wp1);
    pack_plain<<<(ECc * SCc + 255) / 256, 256, 0, stream>>>(f1_w, Wp2, ECc * SCc);
    pack_plain<<<(OCc * ECc + 255) / 256, 256, 0, stream>>>(f2_w, Wp3, OCc * ECc);

    input_conv<<<dim3(Lc / 64, Bc), 256, 0, stream>>>(inputs, input_w, res0);

    float* rin = res0;
    float* rout = res1;
    for (int i = 0; i < NL; ++i) {
        int d = 1 << (i % 10);
        if (i + 1 < NL)
            layer_v3<false><<<dim3(Lc / 64, Bc), 256, 0, stream>>>(
                rin, rout, outsT,
                filter_w + (size_t)i * DCc * RCc * 2,
                gate_w   + (size_t)i * DCc * RCc * 2,
                res_w    + (size_t)i * RCc * DCc,
                cond, gcf_w + i * 5, gcs_w + i * 5, d, i);
        else
            layer_v3<true><<<dim3(Lc / 64, Bc), 256, 0, stream>>>(
                rin, rout, outsT,
                filter_w + (size_t)i * DCc * RCc * 2,
                gate_w   + (size_t)i * DCc * RCc * 2,
                res_w    + (size_t)i * RCc * DCc,
                cond, gcf_w + i * 5, gcs_w + i * 5, d, i);
        float* tmp = rin; rin = rout; rout = tmp;
    }

    // G1: finalT = relu( outsT(12292x640) @ Wp1^T )   -> bf16 [t][1024]
    gemm_mfma<true, true><<<dim3(SCc / 128, Bc * TTILES), 256, 0, stream>>>(
        outsT, Wp1, nullptr, finalT, SCc, KTOT);

    // G2: h1T = relu( finalT @ Wp2^T + f1_b )         -> bf16 [t][512]
    gemm_mfma<true, true><<<dim3(ECc / 128, Bc * TTILES), 256, 0, stream>>>(
        finalT, Wp2, f1_b, h1T, ECc, SCc);

    // G3: out = h1T @ Wp3^T + f2_b                    -> fp32 [t][256] (final layout)
    gemm_mfma<false, false><<<dim3(OCc / 128, Bc * TTILES), 256, 0, stream>>>(
        h1T, Wp3, f2_b, out, OCc, ECc);
}